// Round 1
// baseline (257.641 us; speedup 1.0000x reference)
//
#include <hip/hip_runtime.h>

// FEM Tri3 integrate: out[v] = sum_e detJ(e)/6 * (vals[n0][v]+vals[n1][v]+vals[n2][v])
// (sum_q N_q[q,n] == 1 for each n; w_q == 1/6 -> quadrature collapses exactly)

#define NVALS 8

__global__ __launch_bounds__(256) void fem_integrate_kernel(
    const float* __restrict__ nodal_values,  // (N, 8)
    const float* __restrict__ coords,        // (N, 2)
    const int*   __restrict__ elements,      // (E, 3)
    float* __restrict__ out,                 // (8,)  pre-zeroed
    int E)
{
    float acc[NVALS];
#pragma unroll
    for (int v = 0; v < NVALS; ++v) acc[v] = 0.0f;

    const int stride = gridDim.x * blockDim.x;
    for (int e = blockIdx.x * blockDim.x + threadIdx.x; e < E; e += stride) {
        const int n0 = elements[3 * e + 0];
        const int n1 = elements[3 * e + 1];
        const int n2 = elements[3 * e + 2];

        const float2 c0 = *(const float2*)(coords + 2 * (size_t)n0);
        const float2 c1 = *(const float2*)(coords + 2 * (size_t)n1);
        const float2 c2 = *(const float2*)(coords + 2 * (size_t)n2);

        // J row0 = c1 - c0, J row1 = c2 - c0 ; det = j00*j11 - j01*j10
        const float j00 = c1.x - c0.x, j01 = c1.y - c0.y;
        const float j10 = c2.x - c0.x, j11 = c2.y - c0.y;
        const float wdet = (j00 * j11 - j01 * j10) * (1.0f / 6.0f);

        const float4* p0 = (const float4*)(nodal_values + 8 * (size_t)n0);
        const float4* p1 = (const float4*)(nodal_values + 8 * (size_t)n1);
        const float4* p2 = (const float4*)(nodal_values + 8 * (size_t)n2);
        const float4 a0 = p0[0], b0 = p0[1];
        const float4 a1 = p1[0], b1 = p1[1];
        const float4 a2 = p2[0], b2 = p2[1];

        acc[0] = fmaf(wdet, a0.x + a1.x + a2.x, acc[0]);
        acc[1] = fmaf(wdet, a0.y + a1.y + a2.y, acc[1]);
        acc[2] = fmaf(wdet, a0.z + a1.z + a2.z, acc[2]);
        acc[3] = fmaf(wdet, a0.w + a1.w + a2.w, acc[3]);
        acc[4] = fmaf(wdet, b0.x + b1.x + b2.x, acc[4]);
        acc[5] = fmaf(wdet, b0.y + b1.y + b2.y, acc[5]);
        acc[6] = fmaf(wdet, b0.z + b1.z + b2.z, acc[6]);
        acc[7] = fmaf(wdet, b0.w + b1.w + b2.w, acc[7]);
    }

    // Wave (64-lane) shuffle reduction for each of the 8 accumulators.
#pragma unroll
    for (int v = 0; v < NVALS; ++v) {
        float x = acc[v];
        for (int off = 32; off > 0; off >>= 1) x += __shfl_down(x, off, 64);
        acc[v] = x;
    }

    __shared__ float s[4][NVALS];  // blockDim 256 -> 4 waves
    const int lane = threadIdx.x & 63;
    const int wave = threadIdx.x >> 6;
    if (lane == 0) {
#pragma unroll
        for (int v = 0; v < NVALS; ++v) s[wave][v] = acc[v];
    }
    __syncthreads();

    if (threadIdx.x < NVALS) {
        const float x = s[0][threadIdx.x] + s[1][threadIdx.x] +
                        s[2][threadIdx.x] + s[3][threadIdx.x];
        atomicAdd(&out[threadIdx.x], x);  // device-scope by default on CDNA
    }
}

extern "C" void kernel_launch(void* const* d_in, const int* in_sizes, int n_in,
                              void* d_out, int out_size, void* d_ws, size_t ws_size,
                              hipStream_t stream) {
    const float* nodal_values = (const float*)d_in[0];  // (1e6, 8)
    const float* coords       = (const float*)d_in[1];  // (1e6, 2)
    const int*   elements     = (const int*)d_in[2];    // (2e6, 3)
    float* out = (float*)d_out;

    const int E = in_sizes[2] / 3;

    // d_out is poisoned with 0xAA before every timed launch -> zero it.
    hipMemsetAsync(out, 0, out_size * sizeof(float), stream);

    // 2048 blocks x 256 threads = 524288 threads = full occupancy on 256 CUs
    // (2048 threads/CU at this register footprint); grid-stride ~4 elems/thread.
    const int blocks = 2048;
    fem_integrate_kernel<<<blocks, 256, 0, stream>>>(nodal_values, coords,
                                                     elements, out, E);
}